// Round 1
// baseline (320.909 us; speedup 1.0000x reference)
//
#include <hip/hip_runtime.h>
#include <hip/hip_bf16.h>
#include <math.h>

#define N_CELL 76
#define N_DRUG 764
#define N_ITEM 840
#define BATCH  4096

// ws layout (float offsets)
// pool1 [840][4][64][64]  at 0            (13,762,560 floats)
// pool2 [840][8][32][32]  at 13762560     ( 6,881,280 floats)
// After conv2, pool1 region is dead and re-used:
#define POOL1_OFF 0
#define POOL2_OFF 13762560
#define FCP_OFF   0            // fc partials [16][840][64] = 860,160 floats
#define XFC_OFF   860160       // [840][64]
#define ITEM_OFF  913920       // [840][64]
#define EMB_OFF   967680       // [840][64]
#define LOSS_OFF  1021440      // scalar accumulator

// ---------------- conv1 (1->4ch, 3x3 SAME) + relu + maxpool2 ----------------
__global__ __launch_bounds__(256) void k_conv1(
    const float* __restrict__ cell_pre, const float* __restrict__ drug_pre,
    const float* __restrict__ w1, const float* __restrict__ b1,
    float* __restrict__ pool1, float* __restrict__ loss) {
  __shared__ float img[16384];
  int n = blockIdx.x;
  if (n == 0 && threadIdx.x == 0) *loss = 0.f;  // stream-ordered zero init
  const float* src = (n < N_CELL) ? (cell_pre + (size_t)n * 16384)
                                  : (drug_pre + (size_t)(n - N_CELL) * 16384);
  const float4* s4 = (const float4*)src;
  float4* i4 = (float4*)img;
  for (int i = threadIdx.x; i < 4096; i += 256) i4[i] = s4[i];
  float w[4][9], bb[4];
#pragma unroll
  for (int c = 0; c < 4; ++c) {
    bb[c] = b1[c];
#pragma unroll
    for (int j = 0; j < 9; ++j) w[c][j] = w1[c * 9 + j];
  }
  __syncthreads();
  for (int pos = threadIdx.x; pos < 4096; pos += 256) {
    int py = pos >> 6, px = pos & 63;
    int y0 = 2 * py - 1, x0 = 2 * px - 1;
    float v[4][4];
#pragma unroll
    for (int a = 0; a < 4; ++a) {
      int y = y0 + a;
      bool yok = (y >= 0 && y < 128);
#pragma unroll
      for (int b = 0; b < 4; ++b) {
        int x = x0 + b;
        v[a][b] = (yok && x >= 0 && x < 128) ? img[y * 128 + x] : 0.f;
      }
    }
#pragma unroll
    for (int c = 0; c < 4; ++c) {
      float best = -1e30f;
#pragma unroll
      for (int r = 0; r < 2; ++r)
#pragma unroll
        for (int s = 0; s < 2; ++s) {
          float acc = bb[c];
#pragma unroll
          for (int i = 0; i < 3; ++i)
#pragma unroll
            for (int j = 0; j < 3; ++j)
              acc += v[r + i][s + j] * w[c][i * 3 + j];
          best = fmaxf(best, acc);
        }
      // relu(max) == max(relu) (monotone)
      pool1[(((size_t)n * 4 + c) * 64 + py) * 64 + px] = fmaxf(best, 0.f);
    }
  }
}

// ---------------- conv2 (4->8ch, 3x3 SAME) + relu + maxpool2 ----------------
__global__ __launch_bounds__(256) void k_conv2(
    const float* __restrict__ pool1, const float* __restrict__ w2,
    const float* __restrict__ b2, float* __restrict__ pool2) {
  __shared__ float p1[16384];  // [4][64][64]
  int n = blockIdx.x;
  const float4* s4 = (const float4*)(pool1 + (size_t)n * 16384);
  float4* d4 = (float4*)p1;
  for (int i = threadIdx.x; i < 4096; i += 256) d4[i] = s4[i];
  float bb[8];
#pragma unroll
  for (int o = 0; o < 8; ++o) bb[o] = b2[o];
  __syncthreads();
  for (int pos = threadIdx.x; pos < 1024; pos += 256) {
    int py = pos >> 5, px = pos & 31;
    int y0 = 2 * py - 1, x0 = 2 * px - 1;
    float v[4][4][4];
#pragma unroll
    for (int ic = 0; ic < 4; ++ic)
#pragma unroll
      for (int a = 0; a < 4; ++a) {
        int y = y0 + a;
        bool yok = (y >= 0 && y < 64);
#pragma unroll
        for (int b = 0; b < 4; ++b) {
          int x = x0 + b;
          v[ic][a][b] = (yok && x >= 0 && x < 64) ? p1[(ic * 64 + y) * 64 + x] : 0.f;
        }
      }
    for (int oc = 0; oc < 8; ++oc) {
      float a00 = bb[oc], a01 = bb[oc], a10 = bb[oc], a11 = bb[oc];
#pragma unroll
      for (int ic = 0; ic < 4; ++ic)
#pragma unroll
        for (int i = 0; i < 3; ++i)
#pragma unroll
          for (int j = 0; j < 3; ++j) {
            float w = w2[((oc * 4 + ic) * 3 + i) * 3 + j];
            a00 += v[ic][i][j] * w;
            a01 += v[ic][i][j + 1] * w;
            a10 += v[ic][i + 1][j] * w;
            a11 += v[ic][i + 1][j + 1] * w;
          }
      float m = fmaxf(fmaxf(a00, a01), fmaxf(a10, a11));
      pool2[(((size_t)n * 8 + oc) * 32 + py) * 32 + px] = fmaxf(m, 0.f);
    }
  }
}

// ---------------- FC: [840,8192] @ out_w.T -> k-chunked partials ----------------
// grid (27 img tiles of 32, 16 k-chunks of 512)
__global__ __launch_bounds__(256) void k_fc(
    const float* __restrict__ pool2, const float* __restrict__ out_w,
    float* __restrict__ fc_part) {
  __shared__ float wlT[128 * 65];                 // [kk][o], pad 65 -> conflict-free
  __shared__ __align__(16) float xs[128 * 36];    // [kk][im(32), pad 36 keeps 16B align]
  int it = blockIdx.x, kc = blockIdx.y;
  int im0 = it * 32;
  int tid = threadIdx.x;
  int o = tid & 63, g = tid >> 6;  // g constant per wave -> xs reads broadcast
  float acc[8];
#pragma unroll
  for (int i = 0; i < 8; ++i) acc[i] = 0.f;
  for (int sub = 0; sub < 4; ++sub) {
    int k0 = kc * 512 + sub * 128;
    for (int idx = tid; idx < 8192; idx += 256) {
      int oo = idx >> 7, kk = idx & 127;
      wlT[kk * 65 + oo] = out_w[(size_t)oo * 8192 + k0 + kk];
    }
    for (int idx = tid; idx < 4096; idx += 256) {
      int im = idx >> 7, kk = idx & 127;
      float v = 0.f;
      if (im0 + im < N_ITEM) v = pool2[(size_t)(im0 + im) * 8192 + k0 + kk];
      xs[kk * 36 + im] = v;
    }
    __syncthreads();
    const float* xrow = xs + g * 8;
#pragma unroll 4
    for (int kk = 0; kk < 128; ++kk) {
      float wv = wlT[kk * 65 + o];
      float4 xa = *(const float4*)(xrow + kk * 36);
      float4 xb = *(const float4*)(xrow + kk * 36 + 4);
      acc[0] += xa.x * wv; acc[1] += xa.y * wv; acc[2] += xa.z * wv; acc[3] += xa.w * wv;
      acc[4] += xb.x * wv; acc[5] += xb.y * wv; acc[6] += xb.z * wv; acc[7] += xb.w * wv;
    }
    __syncthreads();
  }
#pragma unroll
  for (int i = 0; i < 8; ++i) {
    int im = im0 + g * 8 + i;
    if (im < N_ITEM) fc_part[((size_t)blockIdx.y * N_ITEM + im) * 64 + o] = acc[i];
  }
}

__global__ __launch_bounds__(256) void k_fc_reduce(
    const float* __restrict__ fc_part, const float* __restrict__ out_b,
    float* __restrict__ xfc) {
  int gid = blockIdx.x * 256 + threadIdx.x;
  if (gid >= N_ITEM * 64) return;
  int img = gid >> 6, o = gid & 63;
  float s = out_b[o];
#pragma unroll
  for (int kc = 0; kc < 16; ++kc)
    s += fc_part[((size_t)kc * N_ITEM + img) * 64 + o];
  xfc[gid] = s;
}

// ---------------- per-group, per-column batch norm (ddof=1) ----------------
__global__ __launch_bounds__(256) void k_norm(
    const float* __restrict__ xfc, float* __restrict__ item) {
  __shared__ float red[256];
  int grp = blockIdx.x >> 6;
  int o = blockIdx.x & 63;
  int base = grp ? N_CELL : 0;
  int N = grp ? N_DRUG : N_CELL;
  int tid = threadIdx.x;
  float s = 0.f;
  for (int i = tid; i < N; i += 256) s += xfc[(size_t)(base + i) * 64 + o];
  red[tid] = s; __syncthreads();
  for (int w = 128; w > 0; w >>= 1) { if (tid < w) red[tid] += red[tid + w]; __syncthreads(); }
  float mean = red[0] / (float)N;
  __syncthreads();
  float sq = 0.f;
  for (int i = tid; i < N; i += 256) {
    float d = xfc[(size_t)(base + i) * 64 + o] - mean;
    sq += d * d;
  }
  red[tid] = sq; __syncthreads();
  for (int w = 128; w > 0; w >>= 1) { if (tid < w) red[tid] += red[tid + w]; __syncthreads(); }
  float inv_std = 1.f / sqrtf(red[0] / (float)(N - 1));
  for (int i = tid; i < N; i += 256)
    item[(size_t)(base + i) * 64 + o] = (xfc[(size_t)(base + i) * 64 + o] - mean) * inv_std;
}

// ---------------- interact (2-hop attention) + agg GEMV ----------------
__global__ __launch_bounds__(256) void k_interact(
    const int* __restrict__ cell_nbr, const int* __restrict__ drug_nbr,
    const float* __restrict__ protein, const float* __restrict__ item,
    const float* __restrict__ agg_w, const float* __restrict__ agg_b,
    float* __restrict__ emb) {
  __shared__ float pb[128 * 65];  // pad 65: scores read = 2 lanes/bank (free)
  __shared__ float item_s[64];
  __shared__ float sc[128];
  __shared__ float hop_out[128];
  __shared__ float red[256];
  int n = blockIdx.x;
  int tid = threadIdx.x;
  const int* nbr = (n < N_CELL) ? (cell_nbr + (size_t)n * 256)
                                : (drug_nbr + (size_t)(n - N_CELL) * 256);
  if (tid < 64) item_s[tid] = item[(size_t)n * 64 + tid];
  __syncthreads();
  for (int h = 0; h < 2; ++h) {
    for (int e = tid; e < 8192; e += 256) {
      int k = e >> 6, d = e & 63;
      int idx = nbr[h * 128 + k];
      pb[k * 65 + d] = protein[(size_t)idx * 64 + d];
    }
    __syncthreads();
    {  // scores[k] = item . pb[k]
      int k = tid >> 1, half = tid & 1;
      int d0 = half * 32;
      float p = 0.f;
#pragma unroll
      for (int d = 0; d < 32; ++d) p += item_s[d0 + d] * pb[k * 65 + d0 + d];
      p += __shfl_xor(p, 1);
      if (half == 0) sc[k] = p;
    }
    __syncthreads();
    if (tid < 64) {  // softmax over 128 (wave 0)
      float a = sc[tid], b = sc[tid + 64];
      float m = fmaxf(a, b);
#pragma unroll
      for (int off = 32; off > 0; off >>= 1) m = fmaxf(m, __shfl_xor(m, off));
      float e0 = __expf(a - m), e1 = __expf(b - m);
      float s = e0 + e1;
#pragma unroll
      for (int off = 32; off > 0; off >>= 1) s += __shfl_xor(s, off);
      float inv = 1.f / s;
      sc[tid] = e0 * inv; sc[tid + 64] = e1 * inv;
    }
    __syncthreads();
    {  // out[d] = sum_k attn[k]*pb[k][d]
      int d = tid & 63, kq = tid >> 6;
      float p = 0.f;
#pragma unroll
      for (int k = 0; k < 32; ++k) {
        int kk = kq * 32 + k;
        p += sc[kk] * pb[kk * 65 + d];
      }
      red[tid] = p;
    }
    __syncthreads();
    if (tid < 64)
      hop_out[h * 64 + tid] = red[tid] + red[tid + 64] + red[tid + 128] + red[tid + 192];
    __syncthreads();
  }
  {  // agg: emb[o] = cat(hop0,hop1) . agg_w[o] + b[o]
    int o = tid & 63, jq = tid >> 6;
    float p = 0.f;
#pragma unroll
    for (int j = 0; j < 32; ++j) {
      int jj = jq * 32 + j;
      p += hop_out[jj] * agg_w[(size_t)o * 128 + jj];
    }
    red[tid] = p;
  }
  __syncthreads();
  if (tid < 64)
    emb[(size_t)n * 64 + tid] =
        red[tid] + red[tid + 64] + red[tid + 128] + red[tid + 192] + agg_b[tid];
}

// ---------------- final scoring, one wave per batch row ----------------
__global__ __launch_bounds__(256) void k_score(
    const int* __restrict__ data, const float* __restrict__ emb,
    const float* __restrict__ comb_w, float* __restrict__ out,
    float* __restrict__ loss) {
  __shared__ float racc[4];
  int tid = threadIdx.x;
  int lane = tid & 63;
  int w = tid >> 6;
  int b = blockIdx.x * 4 + w;
  int c = data[b * 3 + 0], d1 = data[b * 3 + 1], d2 = data[b * 3 + 2];
  float ce = emb[(size_t)c * 64 + lane];
  float e1 = emb[(size_t)(N_CELL + d1) * 64 + lane];
  float e2 = emb[(size_t)(N_CELL + d2) * 64 + lane];
  const float4* wrow = (const float4*)(comb_w + (size_t)lane * 128);
  float comb = 0.f;
#pragma unroll
  for (int j4 = 0; j4 < 16; ++j4) {
    float4 w4 = wrow[j4];
    int j = j4 * 4;
    comb += __shfl(e1, j) * w4.x + __shfl(e1, j + 1) * w4.y +
            __shfl(e1, j + 2) * w4.z + __shfl(e1, j + 3) * w4.w;
  }
#pragma unroll
  for (int j4 = 16; j4 < 32; ++j4) {
    float4 w4 = wrow[j4];
    int j = j4 * 4 - 64;
    comb += __shfl(e2, j) * w4.x + __shfl(e2, j + 1) * w4.y +
            __shfl(e2, j + 2) * w4.z + __shfl(e2, j + 3) * w4.w;
  }
  float th = comb * ce;
  float tx = e1 * e2;
  float rg = ce * ce + e1 * e1 + e2 * e2;
#pragma unroll
  for (int off = 32; off > 0; off >>= 1) {
    th += __shfl_xor(th, off);
    tx += __shfl_xor(tx, off);
    rg += __shfl_xor(rg, off);
  }
  if (lane == 0) { out[b] = th - tx; racc[w] = rg; }
  __syncthreads();
  if (tid == 0) atomicAdd(loss, 0.5f * (racc[0] + racc[1] + racc[2] + racc[3]));
}

// ---------------- node regularization (6 gathered rows) ----------------
__global__ __launch_bounds__(256) void k_nodereg(
    const int* __restrict__ data, const int* __restrict__ cell_nbr,
    const int* __restrict__ drug_nbr, const float* __restrict__ protein,
    float* __restrict__ loss) {
  __shared__ float red[256];
  int j = blockIdx.x;  // 0..5
  int hop = j / 3, which = j % 3;
  int row = data[hop * 3 + which];
  const int* nbr = (which == 0) ? (cell_nbr + (size_t)row * 256)
                                : (drug_nbr + (size_t)row * 256);
  int tid = threadIdx.x;
  float acc = 0.f;
  for (int e = tid; e < 16384; e += 256) {
    int k = e >> 6, d = e & 63;
    float v = protein[(size_t)nbr[k] * 64 + d];
    acc += v * v;
  }
  red[tid] = acc; __syncthreads();
  for (int w = 128; w > 0; w >>= 1) { if (tid < w) red[tid] += red[tid + w]; __syncthreads(); }
  if (tid == 0) atomicAdd(loss, 0.5f * red[0]);
}

__global__ void k_finalize(const float* __restrict__ loss, float* __restrict__ out) {
  if (threadIdx.x == 0) out[BATCH] = loss[0] * (1e-6f / 4096.f);
}

extern "C" void kernel_launch(void* const* d_in, const int* in_sizes, int n_in,
                              void* d_out, int out_size, void* d_ws, size_t ws_size,
                              hipStream_t stream) {
  const int*   data      = (const int*)d_in[0];
  const int*   cell_nbr  = (const int*)d_in[1];
  const int*   drug_nbr  = (const int*)d_in[2];
  const float* protein   = (const float*)d_in[3];
  const float* cell_pre  = (const float*)d_in[4];
  const float* drug_pre  = (const float*)d_in[5];
  const float* w1        = (const float*)d_in[6];
  const float* b1        = (const float*)d_in[7];
  const float* w2        = (const float*)d_in[8];
  const float* b2        = (const float*)d_in[9];
  const float* out_w     = (const float*)d_in[10];
  const float* out_b     = (const float*)d_in[11];
  const float* agg_w     = (const float*)d_in[12];
  const float* agg_b     = (const float*)d_in[13];
  const float* comb_w    = (const float*)d_in[14];
  float* out = (float*)d_out;
  float* ws  = (float*)d_ws;
  float* pool1   = ws + POOL1_OFF;
  float* pool2   = ws + POOL2_OFF;
  float* fc_part = ws + FCP_OFF;
  float* xfc     = ws + XFC_OFF;
  float* item    = ws + ITEM_OFF;
  float* emb     = ws + EMB_OFF;
  float* loss    = ws + LOSS_OFF;

  k_conv1<<<840, 256, 0, stream>>>(cell_pre, drug_pre, w1, b1, pool1, loss);
  k_conv2<<<840, 256, 0, stream>>>(pool1, w2, b2, pool2);
  k_fc<<<dim3(27, 16), 256, 0, stream>>>(pool2, out_w, fc_part);
  k_fc_reduce<<<210, 256, 0, stream>>>(fc_part, out_b, xfc);
  k_norm<<<128, 256, 0, stream>>>(xfc, item);
  k_interact<<<840, 256, 0, stream>>>(cell_nbr, drug_nbr, protein, item, agg_w, agg_b, emb);
  k_score<<<1024, 256, 0, stream>>>(data, emb, comb_w, out, loss);
  k_nodereg<<<6, 256, 0, stream>>>(data, cell_nbr, drug_nbr, protein, loss);
  k_finalize<<<1, 64, 0, stream>>>(loss, out);
}